// Round 6
// baseline (128.080 us; speedup 1.0000x reference)
//
#include <hip/hip_runtime.h>
#include <hip/hip_bf16.h>
#include <cmath>

// Problem constants: V=100000, E=128, B=32, S=1024, N=16
#define NS_ROWS  32768u                 // B*S
#define NS_NEG   16u
#define NS_PAIRS (NS_ROWS * 17u)        // 557056 = 8704 blocks * 64 quads

__device__ __forceinline__ float log_sigmoid_f(float x) {
    return fminf(x, 0.0f) - log1pf(__expf(-fabsf(x)));
}

__device__ __forceinline__ float dot4(const float4 a, const float4 b) {
    return a.x * b.x + a.y * b.y + a.z * b.z + a.w * b.w;
}

// Barrier-free flat-quad kernel: one quad (4 lanes) per (row,target) pair.
//  - lane sub reads 64B line sub of both the W row and the context row, striding
//    4 lines: quad-step = exactly one 64B line -> max coalescer merging
//  - context lines are shared by ~17 quads in the same block -> wave coalescer
//    + L1 make them nearly free; W gathers are the irreducible stream
//  - 16 independent float4 loads per thread, fully unrolled static indices ->
//    deep MLP, no LDS staging, no __syncthreads until the final 4-way reduce
__global__ __launch_bounds__(256) void neg_sampling_kernel(
    const int*   __restrict__ sentence,   // [ROWS]
    const float* __restrict__ context,    // [ROWS, 128]
    const int*   __restrict__ neg,        // [ROWS, 16]
    const float* __restrict__ W,          // [V, 128]
    float*       __restrict__ out)        // scalar
{
    const int tid = threadIdx.x;
    const unsigned pair = (blockIdx.x << 6) | (unsigned)(tid >> 2); // quad id, < 557056
    const int sub = tid & 3;

    const unsigned row = pair / 17u;              // compiler emits mul_hi magic
    const unsigned tgt = pair - row * 17u;

    const int idx = (tgt == 0u) ? sentence[row] : neg[(row << 4) + (tgt - 1u)];

    const float4* __restrict__ wr =
        reinterpret_cast<const float4*>(W) + (size_t)idx * 32 + sub;
    const float4* __restrict__ cr =
        reinterpret_cast<const float4*>(context) + (size_t)row * 32 + sub;

    // Issue all 16 loads (independent, static indices -> registers).
    float4 wv0 = wr[0],  wv1 = wr[4],  wv2 = wr[8],  wv3 = wr[12];
    float4 wv4 = wr[16], wv5 = wr[20], wv6 = wr[24], wv7 = wr[28];
    float4 cv0 = cr[0],  cv1 = cr[4],  cv2 = cr[8],  cv3 = cr[12];
    float4 cv4 = cr[16], cv5 = cr[20], cv6 = cr[24], cv7 = cr[28];

    float acc;
    acc  = dot4(wv0, cv0);
    acc += dot4(wv1, cv1);
    acc += dot4(wv2, cv2);
    acc += dot4(wv3, cv3);
    acc += dot4(wv4, cv4);
    acc += dot4(wv5, cv5);
    acc += dot4(wv6, cv6);
    acc += dot4(wv7, cv7);

    // quad butterfly: full 128-dot in every lane of the quad
    acc += __shfl_xor(acc, 1, 64);
    acc += __shfl_xor(acc, 2, 64);

    float loss = (sub == 0) ? log_sigmoid_f((tgt == 0u) ? acc : -acc) : 0.0f;

    // wave butterfly -> 4-wave block reduce -> one atomic per block
#pragma unroll
    for (int m = 32; m >= 1; m >>= 1) loss += __shfl_xor(loss, m, 64);

    __shared__ float wsum[4];
    const int wave = tid >> 6, lane = tid & 63;
    if (lane == 0) wsum[wave] = loss;
    __syncthreads();
    if (tid == 0) {
        atomicAdd(out, -(wsum[0] + wsum[1] + wsum[2] + wsum[3]));
    }
}

extern "C" void kernel_launch(void* const* d_in, const int* in_sizes, int n_in,
                              void* d_out, int out_size, void* d_ws, size_t ws_size,
                              hipStream_t stream) {
    const int*   sentence = (const int*)d_in[0];
    const float* context  = (const float*)d_in[1];
    const int*   neg      = (const int*)d_in[2];
    const float* W        = (const float*)d_in[3];
    float*       out      = (float*)d_out;

    hipMemsetAsync(out, 0, sizeof(float), stream);

    const int blocks = NS_PAIRS / 64;   // 8704, exact
    neg_sampling_kernel<<<blocks, 256, 0, stream>>>(sentence, context, neg, W, out);
}

// Round 7
// 127.935 us; speedup vs baseline: 1.0011x; 1.0011x over previous
//
#include <hip/hip_runtime.h>
#include <hip/hip_bf16.h>
#include <cmath>

// Problem constants: V=100000, E=128, B=32, S=1024, N=16
#define NS_ROWS  32768u
#define NS_PAIRS (NS_ROWS * 17u)        // 557056 = 8704 blocks * 64 pairs

// Async global->LDS gather, 16B per lane. Global addr is PER-LANE (HW gather);
// LDS dest is wave-uniform base + lane*16.
#define GLOAD_LDS16(g, l)                                                  \
    __builtin_amdgcn_global_load_lds(                                      \
        (const __attribute__((address_space(1))) void*)(g),                \
        (__attribute__((address_space(3))) void*)(l), 16, 0, 0)

__device__ __forceinline__ float log_sigmoid_f(float x) {
    // fast + stable; absmax threshold is ~2% of |out|, precision is ample
    return fminf(x, 0.0f) - __logf(1.0f + __expf(-fabsf(x)));
}

__device__ __forceinline__ float dot4(const float4 a, const float4 b) {
    return a.x * b.x + a.y * b.y + a.z * b.z + a.w * b.w;
}

// One wave = 16 flat (row,target) pairs (quads). All staging via LDS-DMA:
//   - 1 DMA: wave's <=2 context rows (1KB, coalesced)
//   - 8 DMA: 16 W rows gathered as [step][lane] 16B chunks (8KB)
// Counted vmcnt drain (4 -> 0), no VGPR-resident gathers, no block barrier
// until the final 4-way reduce. 36KB LDS/block -> 4 blocks/CU.
__global__ __launch_bounds__(256) void neg_sampling_kernel(
    const int*   __restrict__ sentence,   // [ROWS]
    const float* __restrict__ context,    // [ROWS, 128]
    const int*   __restrict__ neg,        // [ROWS, 16]
    const float* __restrict__ W,          // [V, 128]
    float*       __restrict__ out)        // scalar
{
    __shared__ float wlds[4][8][256];   // [wave][step][lane*4] : 8KB per wave
    __shared__ float clds[4][256];      // [wave][2 rows x 128] : 1KB per wave
    __shared__ float wsum[4];

    const int tid  = threadIdx.x;
    const int w    = tid >> 6;
    const int lane = tid & 63;
    const int sub  = lane & 3;

    const unsigned pair = blockIdx.x * 64u + (unsigned)(tid >> 2);
    const unsigned row  = pair / 17u;
    const unsigned tgt  = pair - row * 17u;
    const int idx = (tgt == 0u) ? sentence[row] : neg[(row << 4) + (tgt - 1u)];

    // wave's base row (pairs p0..p0+15 span <= 2 rows)
    const unsigned r0 = (blockIdx.x * 64u + (unsigned)(w << 4)) / 17u;

    // ---- ctx DMA: lane L reads row r0+(L>>5), 16B chunk (L&31) ----
    unsigned crow = r0 + (unsigned)(lane >> 5);
    if (crow >= NS_ROWS) crow = NS_ROWS - 1u;   // last-block clamp (dup, unused)
    GLOAD_LDS16(context + ((size_t)crow << 7) + ((lane & 31) << 2), &clds[w][0]);

    // ---- W DMAs: step k, lane (q,sub) reads W[idx_q] float4 (4k+sub) ----
    const float* wg = W + ((size_t)idx << 7) + (sub << 2);
#pragma unroll
    for (int k = 0; k < 8; ++k) {
        GLOAD_LDS16(wg + (k << 4), &wlds[w][k][0]);
    }

    const int   local = (int)(row - r0);          // 0 or 1
    const float* cb   = &clds[w][local << 7];

    float acc = 0.0f;

    // ---- first half: ctx + W0..W3 landed (9 issued, <=4 outstanding) ----
    asm volatile("s_waitcnt vmcnt(4)" ::: "memory");
    __builtin_amdgcn_sched_barrier(0);
#pragma unroll
    for (int k = 0; k < 4; ++k) {
        const float4 wv = *reinterpret_cast<const float4*>(&wlds[w][k][lane << 2]);
        const float4 cv = *reinterpret_cast<const float4*>(&cb[(k << 4) + (sub << 2)]);
        acc += dot4(wv, cv);
    }

    // ---- second half: all landed ----
    asm volatile("s_waitcnt vmcnt(0)" ::: "memory");
    __builtin_amdgcn_sched_barrier(0);
#pragma unroll
    for (int k = 4; k < 8; ++k) {
        const float4 wv = *reinterpret_cast<const float4*>(&wlds[w][k][lane << 2]);
        const float4 cv = *reinterpret_cast<const float4*>(&cb[(k << 4) + (sub << 2)]);
        acc += dot4(wv, cv);
    }

    // ---- quad butterfly -> full 128-dot ----
    acc += __shfl_xor(acc, 1, 64);
    acc += __shfl_xor(acc, 2, 64);

    float loss = (sub == 0) ? log_sigmoid_f((tgt == 0u) ? acc : -acc) : 0.0f;

    // ---- wave butterfly -> 4-wave reduce -> one atomic per block ----
#pragma unroll
    for (int m = 32; m >= 1; m >>= 1) loss += __shfl_xor(loss, m, 64);

    if (lane == 0) wsum[w] = loss;
    __syncthreads();
    if (tid == 0) {
        atomicAdd(out, -(wsum[0] + wsum[1] + wsum[2] + wsum[3]));
    }
}

extern "C" void kernel_launch(void* const* d_in, const int* in_sizes, int n_in,
                              void* d_out, int out_size, void* d_ws, size_t ws_size,
                              hipStream_t stream) {
    const int*   sentence = (const int*)d_in[0];
    const float* context  = (const float*)d_in[1];
    const int*   neg      = (const int*)d_in[2];
    const float* W        = (const float*)d_in[3];
    float*       out      = (float*)d_out;

    hipMemsetAsync(out, 0, sizeof(float), stream);

    const int blocks = NS_PAIRS / 64;   // 8704, exact
    neg_sampling_kernel<<<blocks, 256, 0, stream>>>(sentence, context, neg, W, out);
}